// Round 12
// baseline (959.259 us; speedup 1.0000x reference)
//
#include <hip/hip_runtime.h>

#define N_NODES 50000
#define N_EDGES 800000
#define NODE_DIM 128
#define EDGE_DIM 64
#define HIDDEN 256
#define K_E 320   // 2*NODE_DIM + EDGE_DIM
#define K_N 192   // NODE_DIM + EDGE_DIM

typedef __attribute__((ext_vector_type(8))) short bf16x8;
typedef __attribute__((ext_vector_type(4))) float f32x4;
typedef __attribute__((ext_vector_type(16))) float f32x16;
typedef unsigned short u16;
typedef unsigned int u32;

#define MFMA16 __builtin_amdgcn_mfma_f32_16x16x32_bf16
#define MFMA32 __builtin_amdgcn_mfma_f32_32x32x16_bf16

__device__ inline u16 f2bf(float f) {
  u32 u = __builtin_bit_cast(u32, f);
  u += 0x7fffu + ((u >> 16) & 1u);
  return (u16)(u >> 16);
}
__device__ inline float bf2f(u16 u) {
  u32 x = ((u32)u) << 16;
  return __builtin_bit_cast(float, x);
}
__device__ inline u32 pack2(float a, float b) {
  return (u32)f2bf(a) | ((u32)f2bf(b) << 16);
}
__device__ inline void st_bf4(u16* p, float4 v) {
  ushort4 r;
  r.x = f2bf(v.x); r.y = f2bf(v.y); r.z = f2bf(v.z); r.w = f2bf(v.w);
  *reinterpret_cast<ushort4*>(p) = r;
}
// async 16B global->LDS (wave-uniform LDS base + lane*16; per-lane global addr)
__device__ inline void async_copy16(const void* g, void* l) {
  __builtin_amdgcn_global_load_lds(
      (const __attribute__((address_space(1))) unsigned int*)g,
      (__attribute__((address_space(3))) unsigned int*)l, 16, 0, 0);
}

// ---------------- weight prep (+ fused degree histogram) ----------------
// w1y: 32x32x16 A-frag order, ht-major. w2y: layer-2 A-frag order, pi-permuted.
// b1p/b2p: biases pre-permuted to MFMA32 D-row order for contiguous acc init.
__global__ void prep_weights(const float* __restrict__ We1, const float* __restrict__ We2,
                             const float* __restrict__ Wn1, const float* __restrict__ Wn2,
                             const float* __restrict__ be1, const float* __restrict__ be2,
                             const float* __restrict__ nf, const int* __restrict__ dst,
                             u16* __restrict__ w1y, u16* __restrict__ w2y,
                             u16* __restrict__ wn1t, u16* __restrict__ wn2t,
                             float* __restrict__ b1p, float* __restrict__ b2p,
                             u16* __restrict__ nfb, int* __restrict__ hist) {
  const int stride = gridDim.x * blockDim.x;
  const int tid = blockIdx.x * blockDim.x + threadIdx.x;
  for (int i = tid; i < HIDDEN * K_E; i += stride) {
    int jj = i & 7;
    int l = (i >> 3) & 63;
    int rem = i % 10240;
    int kb = rem >> 9;
    int ht = i / 10240;
    int h = ht * 32 + (l & 31);
    int k = kb * 16 + (l >> 5) * 8 + jj;
    w1y[i] = f2bf(We1[k * HIDDEN + h]);
  }
  for (int i = tid; i < EDGE_DIM * HIDDEN; i += stride) {
    int jj = i & 7;
    int l = (i >> 3) & 63;
    int t2 = (i >> 9) & 1;
    int kb2 = i >> 10;
    int out = t2 * 32 + (l & 31);
    int hi = l >> 5;
    int k = kb2 * 16 + (jj & 3) + 8 * (jj >> 2) + 4 * hi;
    w2y[i] = f2bf(We2[k * EDGE_DIM + out]);
  }
  for (int i = tid; i < HIDDEN * K_N; i += stride) {
    int n = i / K_N, k = i % K_N;
    wn1t[i] = f2bf(Wn1[k * HIDDEN + n]);
  }
  for (int i = tid; i < NODE_DIM * HIDDEN; i += stride) {
    int n = i / HIDDEN, k = i % HIDDEN;
    wn2t[i] = f2bf(Wn2[k * NODE_DIM + n]);
  }
  for (int i = tid; i < HIDDEN; i += stride) {
    int ht = i >> 5, hi = (i >> 4) & 1, r = i & 15;
    b1p[i] = be1[ht * 32 + (r & 3) + 8 * (r >> 2) + 4 * hi];
  }
  for (int i = tid; i < EDGE_DIM; i += stride) {
    int t2 = i >> 5, hi = (i >> 4) & 1, r = i & 15;
    b2p[i] = be2[t2 * 32 + (r & 3) + 8 * (r >> 2) + 4 * hi];
  }
  {
    const float4* nf4 = reinterpret_cast<const float4*>(nf);
    for (int i = tid; i < N_NODES * NODE_DIM / 4; i += stride)
      st_bf4(&nfb[i * 4], nf4[i]);
  }
  for (int i = tid; i < N_EDGES; i += stride)
    atomicAdd(&hist[dst[i]], 1);
}

// ---------------- CSR build: 3-phase parallel scan ----------------
#define NB_SCAN 196   // 196*256 = 50176 >= 50000

__global__ void scanA_kernel(const int* __restrict__ hist, int* __restrict__ eid) {
  __shared__ int red[256];
  int gid = blockIdx.x * 256 + threadIdx.x;
  int v = (gid < N_NODES) ? hist[gid] : 0;
  red[threadIdx.x] = v;
  __syncthreads();
  for (int d = 128; d > 0; d >>= 1) {
    if (threadIdx.x < d) red[threadIdx.x] += red[threadIdx.x + d];
    __syncthreads();
  }
  if (threadIdx.x == 0) eid[blockIdx.x] = red[0];   // bsum[b]
}

__global__ void scanB_kernel(int* __restrict__ eid, int* __restrict__ off) {
  __shared__ int ssum[256];
  int tid = threadIdx.x;
  int v = (tid < NB_SCAN) ? eid[tid] : 0;
  ssum[tid] = v;
  __syncthreads();
  for (int d = 1; d < 256; d <<= 1) {
    int t = (tid >= d) ? ssum[tid - d] : 0;
    __syncthreads();
    ssum[tid] += t;
    __syncthreads();
  }
  if (tid < NB_SCAN) eid[256 + tid] = ssum[tid] - v;   // bpre[b] (exclusive)
  if (tid == 255) off[N_NODES] = ssum[255];            // total
}

__global__ void scanC_kernel(const int* __restrict__ hist, const int* __restrict__ eid,
                             int* __restrict__ off, int* __restrict__ cursor,
                             float* __restrict__ e_sum) {
  __shared__ int ssum[256];
  int tid = threadIdx.x;
  int gid = blockIdx.x * 256 + tid;
  int base = eid[256 + blockIdx.x];
  int v = (gid < N_NODES) ? hist[gid] : 0;
  ssum[tid] = v;
  __syncthreads();
  for (int d = 1; d < 256; d <<= 1) {
    int t = (tid >= d) ? ssum[tid - d] : 0;
    __syncthreads();
    ssum[tid] += t;
    __syncthreads();
  }
  if (gid < N_NODES) {
    int o = base + ssum[tid] - v;
    off[gid] = o;
    cursor[gid] = o;
    // fused e_sum zeroing (replaces a memset launch)
    float4 z = {0.f, 0.f, 0.f, 0.f};
    float4* ez = reinterpret_cast<float4*>(e_sum + (size_t)gid * 64);
    #pragma unroll
    for (int q = 0; q < 16; ++q) ez[q] = z;
  }
}

__global__ void scatter_kernel(const int* __restrict__ src, const int* __restrict__ dst,
                               int* __restrict__ cursor, int* __restrict__ eid,
                               int* __restrict__ csr_src, int* __restrict__ csr_dst) {
  int e = blockIdx.x * blockDim.x + threadIdx.x;
  if (e < N_EDGES) {
    int d = dst[e];
    int pos = atomicAdd(&cursor[d], 1);
    eid[pos] = e;
    csr_src[pos] = src[e];
    csr_dst[pos] = d;
  }
}

// ---------------- edge MLP v9: R9 core + async global_load_lds staging -------
// W1 prefetch now via global_load_lds (no staging VGPRs) -> natural register
// use ~64+48AGPR fits the 4-waves/EU budget (cap 128) WITHOUT spilling.
// LDS = 40,960 B exactly (160KB/4) -> 4 blocks/CU. Core math = R8/R9.
__global__ __launch_bounds__(256, 4) void edge_mlp(
    const u16* __restrict__ nfb, const float* __restrict__ ef,
    const int* __restrict__ eid, const int* __restrict__ csr_src,
    const int* __restrict__ csr_dst,
    const u16* __restrict__ w1y, const float* __restrict__ b1p,
    const u16* __restrict__ w2y, const float* __restrict__ b2p,
    float* __restrict__ e_sum, float* __restrict__ out_edge)
{
  __shared__ u16 W1s[2][10240];   // 40,960 B exactly; aliased as f32 bounce later

  const int tid = threadIdx.x;
  const int wv = tid >> 6, lane = tid & 63;
  const int ecol = lane & 31;     // CSR position within wave tile (D col)
  const int hi = lane >> 5;       // k half
  const int e0 = blockIdx.x * 128;
  const int pos = e0 + wv * 32 + ecol;

  // ---- prologue: async-stage W1[ht=0] (20KB) ----
  {
    const char* g = (const char*)w1y;
    char* l = (char*)W1s[0];
    #pragma unroll
    for (int j = 0; j < 5; ++j)
      async_copy16(g + (j * 256 + tid) * 16, l + (j * 256 + (tid & ~63)) * 16);
  }

  // ---- fused edge-feature passthrough (identity, fp32, fully coalesced) ----
  {
    const float4* ef4 = reinterpret_cast<const float4*>(ef);
    float4* oe4 = reinterpret_cast<float4*>(out_edge);
    #pragma unroll
    for (int p = 0; p < 8; ++p) {
      size_t i = (size_t)e0 * 16 + p * 256 + tid;
      oe4[i] = ef4[i];
    }
  }

  // ---- CSR indices (coalesced) ----
  const int e    = eid[pos];
  const int srcn = csr_src[pos];
  const int dstn = csr_dst[pos];   // kept in register; shfl'd in the epilogue

  // ---- gather concat features into B-frags (k = kb*16 + hi*8 + jj) ----
  const int si = srcn << 7;
  const int di = dstn << 7;   // run-local: mostly cache-hit within wave
  bf16x8 efr[20];
  #pragma unroll
  for (int kb = 0; kb < 8; ++kb)
    efr[kb] = *reinterpret_cast<const bf16x8*>(nfb + si + kb * 16 + hi * 8);
  #pragma unroll
  for (int kb = 0; kb < 4; ++kb) {
    const float* ep = ef + (size_t)e * 64 + kb * 16 + hi * 8;
    float4 lo = *reinterpret_cast<const float4*>(ep);
    float4 hv = *reinterpret_cast<const float4*>(ep + 4);
    bf16x8 v;
    v[0] = (short)f2bf(lo.x); v[1] = (short)f2bf(lo.y);
    v[2] = (short)f2bf(lo.z); v[3] = (short)f2bf(lo.w);
    v[4] = (short)f2bf(hv.x); v[5] = (short)f2bf(hv.y);
    v[6] = (short)f2bf(hv.z); v[7] = (short)f2bf(hv.w);
    efr[8 + kb] = v;
  }
  #pragma unroll
  for (int kb = 0; kb < 8; ++kb)
    efr[12 + kb] = *reinterpret_cast<const bf16x8*>(nfb + di + kb * 16 + hi * 8);

  __syncthreads();   // prologue stage complete (vmcnt drained by compiler)

  // ---- layer-2 accumulators, bias-initialized (pre-permuted, contiguous) ----
  f32x16 acc2[2];
  #pragma unroll
  for (int t2 = 0; t2 < 2; ++t2) {
    const float* bp = b2p + t2 * 32 + hi * 16;
    #pragma unroll
    for (int r = 0; r < 16; ++r) acc2[t2][r] = bp[r];
  }

  // ---- ht loop: 8 tiles of 32 hidden; async prefetch into other buffer ----
  #pragma unroll
  for (int ht = 0; ht < 8; ++ht) {
    if (ht < 7) {   // issue next-tile async loads (no VGPR round-trip)
      const char* g = (const char*)(w1y + (ht + 1) * 10240);
      char* l = (char*)W1s[(ht + 1) & 1];
      #pragma unroll
      for (int j = 0; j < 5; ++j)
        async_copy16(g + (j * 256 + tid) * 16, l + (j * 256 + (tid & ~63)) * 16);
    }

    f32x16 acc;
    {
      const float* bp = b1p + ht * 32 + hi * 16;
      #pragma unroll
      for (int r = 0; r < 16; ++r) acc[r] = bp[r];
    }
    const u16* Wb = W1s[ht & 1];
    #pragma unroll
    for (int kb = 0; kb < 20; ++kb) {
      bf16x8 wf = *reinterpret_cast<const bf16x8*>(Wb + (kb * 64 + lane) * 8);
      acc = MFMA32(wf, efr[kb], acc, 0, 0, 0);
    }

    // layer 2: relu+pack acc rows -> B-frag slots (pi matches D row layout)
    #pragma unroll
    for (int s2 = 0; s2 < 2; ++s2) {
      bf16x8 hf;
      u32* hw = reinterpret_cast<u32*>(&hf);
      #pragma unroll
      for (int m = 0; m < 4; ++m)
        hw[m] = pack2(fmaxf(acc[s2 * 8 + 2 * m], 0.f),
                      fmaxf(acc[s2 * 8 + 2 * m + 1], 0.f));
      #pragma unroll
      for (int t2 = 0; t2 < 2; ++t2) {
        bf16x8 wf2 = *reinterpret_cast<const bf16x8*>(
            w2y + ((size_t)((ht * 2 + s2) * 2 + t2) * 64 + lane) * 8);
        acc2[t2] = MFMA32(wf2, hf, acc2[t2], 0, 0, 0);
      }
    }

    if (ht < 7) __syncthreads();   // drain async stage; protect buffer swap
  }

  __syncthreads();   // all waves done reading W1s before bounce aliasing

  // ---- f32 message bounce: wave-private rows, stride 65 (conflict-free) ----
  float* bounce = reinterpret_cast<float*>(W1s);
  {
    const int lp = wv * 32 + ecol;
    #pragma unroll
    for (int t2 = 0; t2 < 2; ++t2)
      #pragma unroll
      for (int r = 0; r < 16; ++r) {
        int o = t2 * 32 + (r & 3) + 8 * (r >> 2) + 4 * hi;
        bounce[lp * 65 + o] = acc2[t2][r];
      }
  }
  // same-wave ds_write -> ds_read: lgkmcnt ordering suffices (no barrier)

  // ---- wave-uniform run-reduction over this wave's 32 positions ----
  {
    const int d = lane;            // dim 0..63
    const int base = wv * 32;      // strip of 32 local positions
    float s = bounce[base * 65 + d];
    int cur = __shfl(dstn, 0, 64);
    #pragma unroll 4
    for (int i = 1; i < 32; ++i) {
      int nx = __shfl(dstn, i, 64);   // wave-uniform
      float v = bounce[(base + i) * 65 + d];
      if (nx == cur) {
        s += v;
      } else {
        atomicAdd(&e_sum[(size_t)cur * 64 + d], s);
        cur = nx;
        s = v;
      }
    }
    atomicAdd(&e_sum[(size_t)cur * 64 + d], s);
  }
}

// ---------------- node MLP + degree gate ----------------
#define SA_N 200
#define SH   264

__global__ __launch_bounds__(256) void node_kernel(
    const float* __restrict__ nf, const float* __restrict__ e_sum,
    const int* __restrict__ hist,
    const u16* __restrict__ w1, const float* __restrict__ b1,
    const u16* __restrict__ w2, const float* __restrict__ b2,
    float* __restrict__ hout)
{
  __shared__ u16 A[64 * SH];
  const int tid = threadIdx.x;
  const int n0 = blockIdx.x * 64;

  const float4* nf4 = reinterpret_cast<const float4*>(nf);
  const float4* es4 = reinterpret_cast<const float4*>(e_sum);

  #pragma unroll
  for (int p = 0; p < 8; ++p) {
    int i = p * 256 + tid;
    int row = i >> 5, c4 = i & 31;
    int rg = min(n0 + row, N_NODES - 1);
    float4 v = nf4[(size_t)rg * 32 + c4];
    st_bf4(&A[row * SA_N + c4 * 4], v);
  }
  #pragma unroll
  for (int p = 0; p < 4; ++p) {
    int i = p * 256 + tid;
    int row = i >> 4, c4 = i & 15;
    int rg = min(n0 + row, N_NODES - 1);
    float4 v = es4[(size_t)rg * 16 + c4];
    st_bf4(&A[row * SA_N + 128 + c4 * 4], v);
  }
  __syncthreads();

  const int wave = tid >> 6, lane = tid & 63;
  const int lr = lane & 15;
  const int lk = (lane >> 4) * 8;

  f32x4 acc[4][4] = {};
  for (int kb = 0; kb < K_N / 32; ++kb) {
    const int ko = kb * 32 + lk;
    bf16x8 a[4], b[4];
    #pragma unroll
    for (int mt = 0; mt < 4; ++mt)
      a[mt] = *reinterpret_cast<const bf16x8*>(&A[(mt * 16 + lr) * SA_N + ko]);
    #pragma unroll
    for (int nt = 0; nt < 4; ++nt)
      b[nt] = *reinterpret_cast<const bf16x8*>(&w1[(size_t)(wave * 64 + nt * 16 + lr) * K_N + ko]);
    #pragma unroll
    for (int mt = 0; mt < 4; ++mt)
      #pragma unroll
      for (int nt = 0; nt < 4; ++nt)
        acc[mt][nt] = MFMA16(a[mt], b[nt], acc[mt][nt], 0, 0, 0);
  }
  __syncthreads();

  u16* H = A;
  #pragma unroll
  for (int mt = 0; mt < 4; ++mt)
    #pragma unroll
    for (int nt = 0; nt < 4; ++nt) {
      int col = wave * 64 + nt * 16 + lr;
      float bias = b1[col];
      #pragma unroll
      for (int j = 0; j < 4; ++j) {
        int row = mt * 16 + (lane >> 4) * 4 + j;
        float h = acc[mt][nt][j] + bias;
        H[row * SH + col] = f2bf(h > 0.f ? h : 0.f);
      }
    }
  __syncthreads();

  f32x4 acc2[8] = {};
  for (int kb = 0; kb < HIDDEN / 32; ++kb) {
    const int ko = kb * 32 + lk;
    bf16x8 a = *reinterpret_cast<const bf16x8*>(&H[(wave * 16 + lr) * SH + ko]);
    #pragma unroll
    for (int nt = 0; nt < 8; ++nt) {
      bf16x8 b = *reinterpret_cast<const bf16x8*>(&w2[(size_t)(nt * 16 + lr) * HIDDEN + ko]);
      acc2[nt] = MFMA16(a, b, acc2[nt], 0, 0, 0);
    }
  }
  #pragma unroll
  for (int nt = 0; nt < 8; ++nt) {
    int col = nt * 16 + lr;
    float bias = b2[col];
    #pragma unroll
    for (int j = 0; j < 4; ++j) {
      int row = wave * 16 + (lane >> 4) * 4 + j;
      int rg = n0 + row;
      if (rg < N_NODES) {
        float v = acc2[nt][j] + bias;
        hout[(size_t)rg * NODE_DIM + col] =
            (hist[rg] != 0) ? v : nf[(size_t)rg * NODE_DIM + col];
      }
    }
  }
}

// ---------------- launcher ----------------
extern "C" void kernel_launch(void* const* d_in, const int* in_sizes, int n_in,
                              void* d_out, int out_size, void* d_ws, size_t ws_size,
                              hipStream_t stream) {
  const float* nf  = (const float*)d_in[0];
  const float* ef  = (const float*)d_in[1];
  const int*   src = (const int*)d_in[2];
  const int*   dst = (const int*)d_in[3];
  const float* We1 = (const float*)d_in[4];
  const float* be1 = (const float*)d_in[5];
  const float* We2 = (const float*)d_in[6];
  const float* be2 = (const float*)d_in[7];
  const float* Wn1 = (const float*)d_in[8];
  const float* bn1 = (const float*)d_in[9];
  const float* Wn2 = (const float*)d_in[10];
  const float* bn2 = (const float*)d_in[11];

  float* hout = (float*)d_out;
  float* out_edge = hout + (size_t)N_NODES * NODE_DIM;

  char* ws = (char*)d_ws;
  int*   hist    = (int*)ws;                     // 200,000 B
  int*   off     = (int*)(ws + 200000);          // 200,004 B
  int*   cursor  = (int*)(ws + 400016);          // 200,000 B
  int*   eid     = (int*)(ws + 600016);          // 3,200,000 B (scan partials early)
  int*   csr_src = (int*)(ws + 3800016);         // 3,200,000 B
  int*   csr_dst = (int*)(ws + 7000016);         // 3,200,000 B
  float* e_sum   = (float*)(ws + 10200016);      // 12,800,000 B (f32)
  u16*   w1y     = (u16*)(ws + 23000016);        // 163,840 B
  u16*   w2y     = (u16*)(ws + 23163856);        // 32,768 B
  u16*   wn1t    = (u16*)(ws + 23196624);        // 98,304 B
  u16*   wn2t    = (u16*)(ws + 23294928);        // 65,536 B
  float* b1p     = (float*)(ws + 23360464);      // 1,024 B
  float* b2p     = (float*)(ws + 23361488);      // 256 B
  u16*   nfb     = (u16*)(ws + 23361744);        // 12,800,000 B (end ~36.2 MB)

  hipMemsetAsync(hist, 0, 200000, stream);
  prep_weights<<<512, 256, 0, stream>>>(We1, We2, Wn1, Wn2, be1, be2, nf, dst,
                                        w1y, w2y, wn1t, wn2t, b1p, b2p, nfb, hist);
  scanA_kernel<<<NB_SCAN, 256, 0, stream>>>(hist, eid);
  scanB_kernel<<<1, 256, 0, stream>>>(eid, off);
  scanC_kernel<<<NB_SCAN, 256, 0, stream>>>(hist, eid, off, cursor, e_sum);
  scatter_kernel<<<(N_EDGES + 255) / 256, 256, 0, stream>>>(src, dst, cursor, eid,
                                                            csr_src, csr_dst);

  edge_mlp<<<N_EDGES / 128, 256, 0, stream>>>(nfb, ef, eid, csr_src, csr_dst,
                                              w1y, b1p, w2y, b2p, e_sum, out_edge);
  node_kernel<<<(N_NODES + 63) / 64, 256, 0, stream>>>(nf, e_sum, hist,
                                                       wn1t, bn1, wn2t, bn2, hout);
}

// Round 13
// 524.243 us; speedup vs baseline: 1.8298x; 1.8298x over previous
//
#include <hip/hip_runtime.h>

#define N_NODES 50000
#define N_EDGES 800000
#define NODE_DIM 128
#define EDGE_DIM 64
#define HIDDEN 256
#define K_N 192   // NODE_DIM + EDGE_DIM

typedef __attribute__((ext_vector_type(8))) short bf16x8;
typedef __attribute__((ext_vector_type(4))) float f32x4;
typedef __attribute__((ext_vector_type(16))) float f32x16;
typedef unsigned short u16;
typedef unsigned int u32;

#define MFMA16 __builtin_amdgcn_mfma_f32_16x16x32_bf16
#define MFMA32 __builtin_amdgcn_mfma_f32_32x32x16_bf16

__device__ inline u16 f2bf(float f) {
  u32 u = __builtin_bit_cast(u32, f);
  u += 0x7fffu + ((u >> 16) & 1u);
  return (u16)(u >> 16);
}
__device__ inline float bf2f(u16 u) {
  u32 x = ((u32)u) << 16;
  return __builtin_bit_cast(float, x);
}
__device__ inline u32 pack2(float a, float b) {
  return (u32)f2bf(a) | ((u32)f2bf(b) << 16);
}
__device__ inline void st_bf4(u16* p, float4 v) {
  ushort4 r;
  r.x = f2bf(v.x); r.y = f2bf(v.y); r.z = f2bf(v.z); r.w = f2bf(v.w);
  *reinterpret_cast<ushort4*>(p) = r;
}

// ---------------- weight prep (+ fused degree histogram) ----------------
// We1 [320][256] splits: rows 0..127 -> W1src, 128..191 -> W1e, 192..319 -> W1dst.
// w1st/w1dt: row-major [256 h][128 k] bf16 (B-operand for the P-GEMMs).
// w1ef: W1e in 32x32x16 A-frag order [ht][kb][lane][jj] (32KB).
// w2y: layer-2 A-frag order, pi-permuted k (unchanged from R9).
// b2p: biases pre-permuted to MFMA32 D-row order.
__global__ void prep_weights(const float* __restrict__ We1, const float* __restrict__ We2,
                             const float* __restrict__ Wn1, const float* __restrict__ Wn2,
                             const float* __restrict__ be2, const int* __restrict__ dst,
                             u16* __restrict__ w1st, u16* __restrict__ w1dt,
                             u16* __restrict__ w1ef, u16* __restrict__ w2y,
                             u16* __restrict__ wn1t, u16* __restrict__ wn2t,
                             float* __restrict__ b2p, int* __restrict__ hist) {
  const int stride = gridDim.x * blockDim.x;
  const int tid = blockIdx.x * blockDim.x + threadIdx.x;
  for (int i = tid; i < HIDDEN * NODE_DIM; i += stride) {
    int h = i >> 7, k = i & 127;
    w1st[i] = f2bf(We1[k * HIDDEN + h]);
    w1dt[i] = f2bf(We1[(192 + k) * HIDDEN + h]);
  }
  for (int i = tid; i < 8 * 4 * 64 * 8; i += stride) {
    int jj = i & 7;
    int l = (i >> 3) & 63;
    int kb = (i >> 9) & 3;
    int ht = i >> 11;
    int h = ht * 32 + (l & 31);
    int kloc = kb * 16 + (l >> 5) * 8 + jj;
    w1ef[i] = f2bf(We1[(128 + kloc) * HIDDEN + h]);
  }
  for (int i = tid; i < EDGE_DIM * HIDDEN; i += stride) {
    int jj = i & 7;
    int l = (i >> 3) & 63;
    int t2 = (i >> 9) & 1;
    int kb2 = i >> 10;
    int out = t2 * 32 + (l & 31);
    int hi = l >> 5;
    int k = kb2 * 16 + (jj & 3) + 8 * (jj >> 2) + 4 * hi;
    w2y[i] = f2bf(We2[k * EDGE_DIM + out]);
  }
  for (int i = tid; i < HIDDEN * K_N; i += stride) {
    int n = i / K_N, k = i % K_N;
    wn1t[i] = f2bf(Wn1[k * HIDDEN + n]);
  }
  for (int i = tid; i < NODE_DIM * HIDDEN; i += stride) {
    int n = i / HIDDEN, k = i % HIDDEN;
    wn2t[i] = f2bf(Wn2[k * NODE_DIM + n]);
  }
  for (int i = tid; i < EDGE_DIM; i += stride) {
    int t2 = i >> 5, hi = (i >> 4) & 1, r = i & 15;
    b2p[i] = be2[t2 * 32 + (r & 3) + 8 * (r >> 2) + 4 * hi];
  }
  for (int i = tid; i < N_EDGES; i += stride)
    atomicAdd(&hist[dst[i]], 1);
}

// ---------------- P-GEMM: P = nf @ W1x (+b1 for src table), permuted bf16 ----
// P[n][c] with c = hi*128 + ht*16 + r  <->  h = ht*32 + (r&3) + 8*(r>>2) + 4*hi
// so the edge kernel's per-(ht,hi) acc-init is one contiguous 32B read.
#define NB_P 782   // ceil(50000/64)
#define SA_P 136
#define SH   264

__global__ __launch_bounds__(256) void pgemm_kernel(
    const float* __restrict__ nf, const u16* __restrict__ w1st,
    const u16* __restrict__ w1dt, const float* __restrict__ be1,
    u16* __restrict__ P_src, u16* __restrict__ P_dst)
{
  const int table = (blockIdx.x >= NB_P) ? 1 : 0;
  const int b = blockIdx.x - table * NB_P;
  const u16* w = table ? w1dt : w1st;
  u16* P = table ? P_dst : P_src;

  __shared__ u16 A[64 * SH];
  const int tid = threadIdx.x;
  const int n0 = b * 64;
  const float4* nf4 = reinterpret_cast<const float4*>(nf);

  #pragma unroll
  for (int p = 0; p < 8; ++p) {
    int i = p * 256 + tid;
    int row = i >> 5, c4 = i & 31;
    int rg = min(n0 + row, N_NODES - 1);
    float4 v = nf4[(size_t)rg * 32 + c4];
    st_bf4(&A[row * SA_P + c4 * 4], v);
  }
  __syncthreads();

  const int wave = tid >> 6, lane = tid & 63;
  const int lr = lane & 15;
  const int lk = (lane >> 4) * 8;

  f32x4 acc[4][4] = {};
  #pragma unroll
  for (int kb = 0; kb < 4; ++kb) {
    const int ko = kb * 32 + lk;
    bf16x8 a[4], bb[4];
    #pragma unroll
    for (int mt = 0; mt < 4; ++mt)
      a[mt] = *reinterpret_cast<const bf16x8*>(&A[(mt * 16 + lr) * SA_P + ko]);
    #pragma unroll
    for (int nt = 0; nt < 4; ++nt)
      bb[nt] = *reinterpret_cast<const bf16x8*>(&w[(size_t)(wave * 64 + nt * 16 + lr) * 128 + ko]);
    #pragma unroll
    for (int mt = 0; mt < 4; ++mt)
      #pragma unroll
      for (int nt = 0; nt < 4; ++nt)
        acc[mt][nt] = MFMA16(a[mt], bb[nt], acc[mt][nt], 0, 0, 0);
  }
  __syncthreads();

  // H (no relu! P is a pre-activation partial); bias only for src table
  u16* H = A;
  #pragma unroll
  for (int mt = 0; mt < 4; ++mt)
    #pragma unroll
    for (int nt = 0; nt < 4; ++nt) {
      int col = wave * 64 + nt * 16 + lr;
      float bias = table ? 0.f : be1[col];
      #pragma unroll
      for (int j = 0; j < 4; ++j) {
        int row = mt * 16 + (lane >> 4) * 4 + j;
        H[row * SH + col] = f2bf(acc[mt][nt][j] + bias);
      }
    }
  __syncthreads();

  // permuted coalesced store: 64 rows x 64 ushort4 groups
  #pragma unroll
  for (int p = 0; p < 16; ++p) {
    int u = p * 256 + tid;
    int row = u >> 6, cg = u & 63;
    int hi = cg >> 5, ht = (cg >> 2) & 7, q = cg & 3;
    int hbase = ht * 32 + 8 * q + 4 * hi;
    int n = n0 + row;
    if (n < N_NODES) {
      ushort4 v = *reinterpret_cast<const ushort4*>(&H[row * SH + hbase]);
      *reinterpret_cast<ushort4*>(&P[(size_t)n * 256 + cg * 4]) = v;
    }
  }
}

// ---------------- CSR build: 3-phase parallel scan ----------------
#define NB_SCAN 196   // 196*256 = 50176 >= 50000

__global__ void scanA_kernel(const int* __restrict__ hist, int* __restrict__ eid) {
  __shared__ int red[256];
  int gid = blockIdx.x * 256 + threadIdx.x;
  int v = (gid < N_NODES) ? hist[gid] : 0;
  red[threadIdx.x] = v;
  __syncthreads();
  for (int d = 128; d > 0; d >>= 1) {
    if (threadIdx.x < d) red[threadIdx.x] += red[threadIdx.x + d];
    __syncthreads();
  }
  if (threadIdx.x == 0) eid[blockIdx.x] = red[0];   // bsum[b]
}

__global__ void scanB_kernel(int* __restrict__ eid, int* __restrict__ off) {
  __shared__ int ssum[256];
  int tid = threadIdx.x;
  int v = (tid < NB_SCAN) ? eid[tid] : 0;
  ssum[tid] = v;
  __syncthreads();
  for (int d = 1; d < 256; d <<= 1) {
    int t = (tid >= d) ? ssum[tid - d] : 0;
    __syncthreads();
    ssum[tid] += t;
    __syncthreads();
  }
  if (tid < NB_SCAN) eid[256 + tid] = ssum[tid] - v;   // bpre[b] (exclusive)
  if (tid == 255) off[N_NODES] = ssum[255];            // total
}

__global__ void scanC_kernel(const int* __restrict__ hist, const int* __restrict__ eid,
                             int* __restrict__ off, int* __restrict__ cursor,
                             float* __restrict__ e_sum) {
  __shared__ int ssum[256];
  int tid = threadIdx.x;
  int gid = blockIdx.x * 256 + tid;
  int base = eid[256 + blockIdx.x];
  int v = (gid < N_NODES) ? hist[gid] : 0;
  ssum[tid] = v;
  __syncthreads();
  for (int d = 1; d < 256; d <<= 1) {
    int t = (tid >= d) ? ssum[tid - d] : 0;
    __syncthreads();
    ssum[tid] += t;
    __syncthreads();
  }
  if (gid < N_NODES) {
    int o = base + ssum[tid] - v;
    off[gid] = o;
    cursor[gid] = o;
    float4 z = {0.f, 0.f, 0.f, 0.f};
    float4* ez = reinterpret_cast<float4*>(e_sum + (size_t)gid * 64);
    #pragma unroll
    for (int q = 0; q < 16; ++q) ez[q] = z;
  }
}

__global__ void scatter_kernel(const int* __restrict__ src, const int* __restrict__ dst,
                               int* __restrict__ cursor, int* __restrict__ eid,
                               int* __restrict__ csr_src, int* __restrict__ csr_dst) {
  int e = blockIdx.x * blockDim.x + threadIdx.x;
  if (e < N_EDGES) {
    int d = dst[e];
    int pos = atomicAdd(&cursor[d], 1);
    eid[pos] = e;
    csr_src[pos] = src[e];
    csr_dst[pos] = d;
  }
}

// ---------------- edge MLP v10: K=64 via algebraic split ----------------
// layer1 = P_src[src] + P_dst[dst] + e @ W1e  (P tables precomputed, permuted,
// bias folded into P_src). Per ht: 2x32B P gathers init acc, 4 MFMA32 (K=64),
// then layer 2 in-register (pi-permuted W2) as in R9. W1e (32KB) staged once
// in LDS; no double-buffer, no per-ht barriers. efr state: 16 VGPRs.
__global__ __launch_bounds__(256, 4) void edge_mlp(
    const u16* __restrict__ P_src, const u16* __restrict__ P_dst,
    const float* __restrict__ ef,
    const int* __restrict__ eid, const int* __restrict__ csr_src,
    const int* __restrict__ csr_dst,
    const u16* __restrict__ w1ef, const u16* __restrict__ w2y,
    const float* __restrict__ b2p,
    float* __restrict__ e_sum, float* __restrict__ out_edge)
{
  __shared__ char shmem[33280];                     // 33,280 B
  u16* W1e = reinterpret_cast<u16*>(shmem);         // 32,768 B (phase 1)
  float* bounce = reinterpret_cast<float*>(shmem);  // 128x65 f32 (phase 2, aliased)

  const int tid = threadIdx.x;
  const int wv = tid >> 6, lane = tid & 63;
  const int ecol = lane & 31;     // CSR position within wave tile (D col)
  const int hi = lane >> 5;       // k half
  const int e0 = blockIdx.x * 128;
  const int pos = e0 + wv * 32 + ecol;

  // ---- stage W1e fragments (32KB, once) ----
  {
    const uint4* s = reinterpret_cast<const uint4*>(w1ef);
    uint4* d = reinterpret_cast<uint4*>(W1e);
    #pragma unroll
    for (int j = 0; j < 8; ++j) d[j * 256 + tid] = s[j * 256 + tid];
  }

  // ---- fused edge-feature passthrough (identity, fp32, fully coalesced) ----
  {
    const float4* ef4 = reinterpret_cast<const float4*>(ef);
    float4* oe4 = reinterpret_cast<float4*>(out_edge);
    #pragma unroll
    for (int p = 0; p < 8; ++p) {
      size_t i = (size_t)e0 * 16 + p * 256 + tid;
      oe4[i] = ef4[i];
    }
  }

  // ---- CSR indices (coalesced) ----
  const int e    = eid[pos];
  const int srcn = csr_src[pos];
  const int dstn = csr_dst[pos];   // register; shfl'd in the epilogue

  // ---- gather edge features into B-frags (k = kb*16 + hi*8 + jj), K=64 ----
  bf16x8 efr[4];
  #pragma unroll
  for (int kb = 0; kb < 4; ++kb) {
    const float* ep = ef + (size_t)e * 64 + kb * 16 + hi * 8;
    float4 lo = *reinterpret_cast<const float4*>(ep);
    float4 hv = *reinterpret_cast<const float4*>(ep + 4);
    bf16x8 v;
    v[0] = (short)f2bf(lo.x); v[1] = (short)f2bf(lo.y);
    v[2] = (short)f2bf(lo.z); v[3] = (short)f2bf(lo.w);
    v[4] = (short)f2bf(hv.x); v[5] = (short)f2bf(hv.y);
    v[6] = (short)f2bf(hv.z); v[7] = (short)f2bf(hv.w);
    efr[kb] = v;
  }

  __syncthreads();   // W1e staged

  // ---- layer-2 accumulators, bias-initialized ----
  f32x16 acc2[2];
  #pragma unroll
  for (int t2 = 0; t2 < 2; ++t2) {
    const float* bp = b2p + t2 * 32 + hi * 16;
    #pragma unroll
    for (int r = 0; r < 16; ++r) acc2[t2][r] = bp[r];
  }

  const u16* psb = P_src + (size_t)srcn * 256 + hi * 128;
  const u16* pdb = P_dst + (size_t)dstn * 256 + hi * 128;

  // ---- ht loop: 8 tiles of 32 hidden ----
  #pragma unroll
  for (int ht = 0; ht < 8; ++ht) {
    // acc init: P_src + P_dst partials (32B contiguous each; b1 already in P_src)
    bf16x8 a0 = *reinterpret_cast<const bf16x8*>(psb + ht * 16);
    bf16x8 a1 = *reinterpret_cast<const bf16x8*>(psb + ht * 16 + 8);
    bf16x8 d0 = *reinterpret_cast<const bf16x8*>(pdb + ht * 16);
    bf16x8 d1 = *reinterpret_cast<const bf16x8*>(pdb + ht * 16 + 8);
    f32x16 acc;
    #pragma unroll
    for (int r = 0; r < 8; ++r) {
      acc[r]     = bf2f((u16)a0[r]) + bf2f((u16)d0[r]);
      acc[8 + r] = bf2f((u16)a1[r]) + bf2f((u16)d1[r]);
    }

    // layer 1: K=64 (4 kb), W1e frags from LDS
    #pragma unroll
    for (int kb = 0; kb < 4; ++kb) {
      bf16x8 wf = *reinterpret_cast<const bf16x8*>(W1e + ((ht * 4 + kb) * 64 + lane) * 8);
      acc = MFMA32(wf, efr[kb], acc, 0, 0, 0);
    }

    // layer 2: relu+pack acc rows -> B-frag slots (pi matches D row layout)
    #pragma unroll
    for (int s2 = 0; s2 < 2; ++s2) {
      bf16x8 hf;
      u32* hw = reinterpret_cast<u32*>(&hf);
      #pragma unroll
      for (int m = 0; m < 4; ++m)
        hw[m] = pack2(fmaxf(acc[s2 * 8 + 2 * m], 0.f),
                      fmaxf(acc[s2 * 8 + 2 * m + 1], 0.f));
      #pragma unroll
      for (int t2 = 0; t2 < 2; ++t2) {
        bf16x8 wf2 = *reinterpret_cast<const bf16x8*>(
            w2y + ((size_t)((ht * 2 + s2) * 2 + t2) * 64 + lane) * 8);
        acc2[t2] = MFMA32(wf2, hf, acc2[t2], 0, 0, 0);
      }
    }
  }

  __syncthreads();   // all waves done reading W1e before bounce aliasing

  // ---- f32 message bounce: wave-private rows, stride 65 (conflict-free) ----
  {
    const int lp = wv * 32 + ecol;
    #pragma unroll
    for (int t2 = 0; t2 < 2; ++t2)
      #pragma unroll
      for (int r = 0; r < 16; ++r) {
        int o = t2 * 32 + (r & 3) + 8 * (r >> 2) + 4 * hi;
        bounce[lp * 65 + o] = acc2[t2][r];
      }
  }
  // same-wave ds_write -> ds_read: lgkmcnt ordering suffices (no barrier)

  // ---- wave-uniform run-reduction over this wave's 32 positions ----
  {
    const int d = lane;            // dim 0..63
    const int base = wv * 32;      // strip of 32 local positions
    float s = bounce[base * 65 + d];
    int cur = __shfl(dstn, 0, 64);
    #pragma unroll 4
    for (int i = 1; i < 32; ++i) {
      int nx = __shfl(dstn, i, 64);   // wave-uniform
      float v = bounce[(base + i) * 65 + d];
      if (nx == cur) {
        s += v;
      } else {
        atomicAdd(&e_sum[(size_t)cur * 64 + d], s);
        cur = nx;
        s = v;
      }
    }
    atomicAdd(&e_sum[(size_t)cur * 64 + d], s);
  }
}

// ---------------- node MLP + degree gate ----------------
#define SA_N 200

__global__ __launch_bounds__(256) void node_kernel(
    const float* __restrict__ nf, const float* __restrict__ e_sum,
    const int* __restrict__ hist,
    const u16* __restrict__ w1, const float* __restrict__ b1,
    const u16* __restrict__ w2, const float* __restrict__ b2,
    float* __restrict__ hout)
{
  __shared__ u16 A[64 * SH];
  const int tid = threadIdx.x;
  const int n0 = blockIdx.x * 64;

  const float4* nf4 = reinterpret_cast<const float4*>(nf);
  const float4* es4 = reinterpret_cast<const float4*>(e_sum);

  #pragma unroll
  for (int p = 0; p < 8; ++p) {
    int i = p * 256 + tid;
    int row = i >> 5, c4 = i & 31;
    int rg = min(n0 + row, N_NODES - 1);
    float4 v = nf4[(size_t)rg * 32 + c4];
    st_bf4(&A[row * SA_N + c4 * 4], v);
  }
  #pragma unroll
  for (int p = 0; p < 4; ++p) {
    int i = p * 256 + tid;
    int row = i >> 4, c4 = i & 15;
    int rg = min(n0 + row, N_NODES - 1);
    float4 v = es4[(size_t)rg * 16 + c4];
    st_bf4(&A[row * SA_N + 128 + c4 * 4], v);
  }
  __syncthreads();

  const int wave = tid >> 6, lane = tid & 63;
  const int lr = lane & 15;
  const int lk = (lane >> 4) * 8;

  f32x4 acc[4][4] = {};
  for (int kb = 0; kb < K_N / 32; ++kb) {
    const int ko = kb * 32 + lk;
    bf16x8 a[4], b[4];
    #pragma unroll
    for (int mt = 0; mt < 4; ++mt)
      a[mt] = *reinterpret_cast<const bf16x8*>(&A[(mt * 16 + lr) * SA_N + ko]);
    #pragma unroll
    for (int nt = 0; nt < 4; ++nt)
      b[nt] = *reinterpret_cast<const bf16x8*>(&w1[(size_t)(wave * 64 + nt * 16 + lr) * K_N + ko]);
    #pragma unroll
    for (int mt = 0; mt < 4; ++mt)
      #pragma unroll
      for (int nt = 0; nt < 4; ++nt)
        acc[mt][nt] = MFMA16(a[mt], b[nt], acc[mt][nt], 0, 0, 0);
  }
  __syncthreads();

  u16* H = A;
  #pragma unroll
  for (int mt = 0; mt < 4; ++mt)
    #pragma unroll
    for (int nt = 0; nt < 4; ++nt) {
      int col = wave * 64 + nt * 16 + lr;
      float bias = b1[col];
      #pragma unroll
      for (int j = 0; j < 4; ++j) {
        int row = mt * 16 + (lane >> 4) * 4 + j;
        float h = acc[mt][nt][j] + bias;
        H[row * SH + col] = f2bf(h > 0.f ? h : 0.f);
      }
    }
  __syncthreads();

  f32x4 acc2[8] = {};
  for (int kb = 0; kb < HIDDEN / 32; ++kb) {
    const int ko = kb * 32 + lk;
    bf16x8 a = *reinterpret_cast<const bf16x8*>(&H[(wave * 16 + lr) * SH + ko]);
    #pragma unroll
    for (int nt = 0; nt < 8; ++nt) {
      bf16x8 b = *reinterpret_cast<const bf16x8*>(&w2[(size_t)(nt * 16 + lr) * HIDDEN + ko]);
      acc2[nt] = MFMA16(a, b, acc2[nt], 0, 0, 0);
    }
  }
  #pragma unroll
  for (int nt = 0; nt < 8; ++nt) {
    int col = nt * 16 + lr;
    float bias = b2[col];
    #pragma unroll
    for (int j = 0; j < 4; ++j) {
      int row = wave * 16 + (lane >> 4) * 4 + j;
      int rg = n0 + row;
      if (rg < N_NODES) {
        float v = acc2[nt][j] + bias;
        hout[(size_t)rg * NODE_DIM + col] =
            (hist[rg] != 0) ? v : nf[(size_t)rg * NODE_DIM + col];
      }
    }
  }
}

// ---------------- launcher ----------------
extern "C" void kernel_launch(void* const* d_in, const int* in_sizes, int n_in,
                              void* d_out, int out_size, void* d_ws, size_t ws_size,
                              hipStream_t stream) {
  const float* nf  = (const float*)d_in[0];
  const float* ef  = (const float*)d_in[1];
  const int*   src = (const int*)d_in[2];
  const int*   dst = (const int*)d_in[3];
  const float* We1 = (const float*)d_in[4];
  const float* be1 = (const float*)d_in[5];
  const float* We2 = (const float*)d_in[6];
  const float* be2 = (const float*)d_in[7];
  const float* Wn1 = (const float*)d_in[8];
  const float* bn1 = (const float*)d_in[9];
  const float* Wn2 = (const float*)d_in[10];
  const float* bn2 = (const float*)d_in[11];

  float* hout = (float*)d_out;
  float* out_edge = hout + (size_t)N_NODES * NODE_DIM;

  char* ws = (char*)d_ws;
  int*   hist    = (int*)ws;                     // 200,000 B
  int*   off     = (int*)(ws + 200000);          // 200,004 B
  int*   cursor  = (int*)(ws + 400016);          // 200,000 B
  int*   eid     = (int*)(ws + 600016);          // 3,200,000 B (scan partials early)
  int*   csr_src = (int*)(ws + 3800016);         // 3,200,000 B
  int*   csr_dst = (int*)(ws + 7000016);         // 3,200,000 B
  float* e_sum   = (float*)(ws + 10200016);      // 12,800,000 B (f32)
  u16*   w1ef    = (u16*)(ws + 23000016);        // 32,768 B
  u16*   w1st    = (u16*)(ws + 23032784);        // 65,536 B
  u16*   w1dt    = (u16*)(ws + 23098320);        // 65,536 B
  u16*   w2y     = (u16*)(ws + 23163856);        // 32,768 B
  u16*   wn1t    = (u16*)(ws + 23196624);        // 98,304 B
  u16*   wn2t    = (u16*)(ws + 23294928);        // 65,536 B
  float* b2p     = (float*)(ws + 23360464);      // 256 B
  u16*   P_src   = (u16*)(ws + 23360720);        // 25,600,000 B
  u16*   P_dst   = (u16*)(ws + 48960720);        // 25,600,000 B (end ~74.6 MB)

  hipMemsetAsync(hist, 0, 200000, stream);
  prep_weights<<<512, 256, 0, stream>>>(We1, We2, Wn1, Wn2, be2, dst,
                                        w1st, w1dt, w1ef, w2y, wn1t, wn2t,
                                        b2p, hist);
  pgemm_kernel<<<2 * NB_P, 256, 0, stream>>>(nf, w1st, w1dt, be1, P_src, P_dst);
  scanA_kernel<<<NB_SCAN, 256, 0, stream>>>(hist, eid);
  scanB_kernel<<<1, 256, 0, stream>>>(eid, off);
  scanC_kernel<<<NB_SCAN, 256, 0, stream>>>(hist, eid, off, cursor, e_sum);
  scatter_kernel<<<(N_EDGES + 255) / 256, 256, 0, stream>>>(src, dst, cursor, eid,
                                                            csr_src, csr_dst);

  edge_mlp<<<N_EDGES / 128, 256, 0, stream>>>(P_src, P_dst, ef, eid, csr_src,
                                              csr_dst, w1ef, w2y, b2p,
                                              e_sum, out_edge);
  node_kernel<<<(N_NODES + 63) / 64, 256, 0, stream>>>(nf, e_sum, hist,
                                                       wn1t, bn1, wn2t, bn2, hout);
}